// Round 1
// baseline (507.659 us; speedup 1.0000x reference)
//
#include <hip/hip_runtime.h>
#include <hip/hip_bf16.h>
#include <cstdint>
#include <cstddef>

typedef __bf16 bf16;
typedef __bf16 bf16x8 __attribute__((ext_vector_type(8)));
typedef __bf16 bf16x4 __attribute__((ext_vector_type(4)));
typedef float f32x4 __attribute__((ext_vector_type(4)));

static constexpr int BATCH = 2;
static constexpr int SEQ = 2048;
static constexpr int DMODEL = 2048;
static constexpr int NH = 16;
static constexpr int HD = 128;          // head dim
static constexpr int MROWS = BATCH * SEQ; // 4096

// ---------------- fp32 -> bf16 convert ----------------
__global__ void cvt_kernel(const float* __restrict__ src, bf16* __restrict__ dst, int n4) {
  int i = blockIdx.x * blockDim.x + threadIdx.x;
  if (i < n4) {
    float4 f = reinterpret_cast<const float4*>(src)[i];
    bf16x4 o;
    o.x = (bf16)f.x; o.y = (bf16)f.y; o.z = (bf16)f.z; o.w = (bf16)f.w;
    reinterpret_cast<bf16x4*>(dst)[i] = o;
  }
}

// ---------------- GEMM: C = A(MxK,row) * W(NxK,row)^T ----------------
// 128x128 tile, 4 waves 2x2, each wave 64x64 (4x4 of 16x16x32 mfma), BK=64.
// Verified fragment layouts (learn_hip m89/m91):
//   A frag: lane holds A[m=lane&15][k=quad*8+j]   (8 contiguous bf16)
//   B frag: lane holds B[k=quad*8+j][n=lane&15] = W[lane&15][k]  (8 contiguous)
//   C/D:    lane reg j holds C[row=quad*4+j][col=lane&15]
enum { MODE_Q = 0, MODE_K = 1, MODE_V = 2, MODE_OUT = 3 };

template <int MODE>
__global__ __launch_bounds__(256, 2) void gemm_bt(
    const bf16* __restrict__ A, const bf16* __restrict__ Bw,
    void* __restrict__ Cout) {
  constexpr int Kd = DMODEL;
  __shared__ __align__(16) bf16 As[128][72];  // +8 pad, keeps rows 16B-aligned (144B)
  __shared__ __align__(16) bf16 Bs[128][72];
  const int n0 = blockIdx.x * 128;
  const int m0 = blockIdx.y * 128;
  const int tid = threadIdx.x;
  const int wave = tid >> 6;
  const int lane = tid & 63;
  const int quad = lane >> 4;
  const int l16 = lane & 15;
  const int wm = (wave >> 1) * 64;
  const int wn = (wave & 1) * 64;
  const int sr = tid >> 3;          // staging row 0..31
  const int sc = (tid & 7) * 8;     // staging col (8 bf16 = 16B chunks)

  f32x4 acc[4][4] = {};
  for (int kt = 0; kt < Kd; kt += 64) {
#pragma unroll
    for (int i = 0; i < 4; i++) {
      int r = sr + i * 32;
      *reinterpret_cast<uint4*>(&As[r][sc]) =
          *reinterpret_cast<const uint4*>(&A[(size_t)(m0 + r) * Kd + kt + sc]);
      *reinterpret_cast<uint4*>(&Bs[r][sc]) =
          *reinterpret_cast<const uint4*>(&Bw[(size_t)(n0 + r) * Kd + kt + sc]);
    }
    __syncthreads();
#pragma unroll
    for (int ks = 0; ks < 2; ks++) {
      bf16x8 af[4], bfr[4];
#pragma unroll
      for (int t = 0; t < 4; t++)
        af[t] = *reinterpret_cast<const bf16x8*>(&As[wm + t * 16 + l16][ks * 32 + quad * 8]);
#pragma unroll
      for (int t = 0; t < 4; t++)
        bfr[t] = *reinterpret_cast<const bf16x8*>(&Bs[wn + t * 16 + l16][ks * 32 + quad * 8]);
#pragma unroll
      for (int tm = 0; tm < 4; tm++)
#pragma unroll
        for (int tn = 0; tn < 4; tn++)
          acc[tm][tn] = __builtin_amdgcn_mfma_f32_16x16x32_bf16(af[tm], bfr[tn], acc[tm][tn], 0, 0, 0);
    }
    __syncthreads();
  }
  // epilogue
#pragma unroll
  for (int tm = 0; tm < 4; tm++) {
#pragma unroll
    for (int tn = 0; tn < 4; tn++) {
      const int row0 = m0 + wm + tm * 16 + quad * 4;
      const int col = n0 + wn + tn * 16 + l16;
      if constexpr (MODE == MODE_OUT) {
        float* O = (float*)Cout;
#pragma unroll
        for (int j = 0; j < 4; j++)
          O[(size_t)(row0 + j) * DMODEL + col] = acc[tm][tn][j];
      } else if constexpr (MODE == MODE_V) {
        // V^T layout: Vt[b][h][dd][s], 4 consecutive s per lane -> 8B store
        bf16* O = (bf16*)Cout;
        const int b = row0 >> 11, s = row0 & 2047;
        const int h = col >> 7, dd = col & 127;
        bf16x4 pk;
#pragma unroll
        for (int j = 0; j < 4; j++) pk[j] = (bf16)acc[tm][tn][j];
        *reinterpret_cast<bf16x4*>(
            &O[((size_t)(b * NH + h) * HD + dd) * SEQ + s]) = pk;
      } else {
        // Q/K layout: [b][h][s][dd]
        bf16* O = (bf16*)Cout;
        constexpr float scale = (MODE == MODE_Q) ? 0.08838834764831845f : 1.0f;
#pragma unroll
        for (int j = 0; j < 4; j++) {
          const int row = row0 + j;
          const int b = row >> 11, s = row & 2047;
          const int h = col >> 7, dd = col & 127;
          O[((size_t)(b * NH + h) * SEQ + s) * HD + dd] = (bf16)(acc[tm][tn][j] * scale);
        }
      }
    }
  }
}

// ---------------- flash attention ----------------
// grid (16 q-tiles, 32 bh). block 256 = 4 waves; wave handles 32 q-rows x 128 d.
// K/V staged per 64-key tile; online softmax; P LDS round-trip (C-layout -> A-layout).
__global__ __launch_bounds__(256, 2) void attn_kernel(
    const bf16* __restrict__ Q, const bf16* __restrict__ K,
    const bf16* __restrict__ Vt, bf16* __restrict__ Y) {
  const int qt = (int)gridDim.x - 1 - (int)blockIdx.x; // long blocks launch first
  const int bh = blockIdx.y;
  const int q0 = qt * 128;
  __shared__ __align__(16) bf16 Ks[64][136];    // keys x d
  __shared__ __align__(16) bf16 Vts[128][72];   // d x keys
  __shared__ __align__(16) bf16 Ps[4][32][72];  // per-wave P
  const int tid = threadIdx.x;
  const int wave = tid >> 6;
  const int lane = tid & 63;
  const int quad = lane >> 4;
  const int l16 = lane & 15;

  // Q fragments in registers (A-layout), rows = wave*32 + tm*16 + l16
  const bf16* Qw = Q + ((size_t)bh * SEQ + q0 + wave * 32) * HD;
  bf16x8 qf[2][4];
#pragma unroll
  for (int tm = 0; tm < 2; tm++)
#pragma unroll
    for (int kk = 0; kk < 4; kk++)
      qf[tm][kk] = *reinterpret_cast<const bf16x8*>(
          &Qw[(size_t)(tm * 16 + l16) * HD + kk * 32 + quad * 8]);

  f32x4 oacc[2][8] = {};
  float mrow[2][4], lrow[2][4];
#pragma unroll
  for (int tm = 0; tm < 2; tm++)
#pragma unroll
    for (int j = 0; j < 4; j++) { mrow[tm][j] = -3.0e38f; lrow[tm][j] = 0.f; }

  const bf16* Kbh = K + (size_t)bh * SEQ * HD;
  const bf16* Vbh = Vt + (size_t)bh * HD * SEQ;
  const int kend = q0 + 128;  // causal: keys < q0+128 only
  for (int kt = 0; kt < kend; kt += 64) {
    // stage K tile (64x128) and Vt tile (128x64)
#pragma unroll
    for (int i = 0; i < 4; i++) {
      int idx = tid + i * 256;
      int r = idx >> 4, c = (idx & 15) * 8;
      *reinterpret_cast<uint4*>(&Ks[r][c]) =
          *reinterpret_cast<const uint4*>(&Kbh[(size_t)(kt + r) * HD + c]);
    }
#pragma unroll
    for (int i = 0; i < 4; i++) {
      int idx = tid + i * 256;
      int r = idx >> 3, c = (idx & 7) * 8;
      *reinterpret_cast<uint4*>(&Vts[r][c]) =
          *reinterpret_cast<const uint4*>(&Vbh[(size_t)r * SEQ + kt + c]);
    }
    __syncthreads();

    // S = Q K^T : 2x4 tiles of 16x16 per wave
    f32x4 sacc[2][4] = {};
#pragma unroll
    for (int kk = 0; kk < 4; kk++) {
      bf16x8 kf[4];
#pragma unroll
      for (int tn = 0; tn < 4; tn++)
        kf[tn] = *reinterpret_cast<const bf16x8*>(&Ks[tn * 16 + l16][kk * 32 + quad * 8]);
#pragma unroll
      for (int tm = 0; tm < 2; tm++)
#pragma unroll
        for (int tn = 0; tn < 4; tn++)
          sacc[tm][tn] = __builtin_amdgcn_mfma_f32_16x16x32_bf16(qf[tm][kk], kf[tn], sacc[tm][tn], 0, 0, 0);
    }

    // causal mask + online softmax per q-row
#pragma unroll
    for (int tm = 0; tm < 2; tm++) {
#pragma unroll
      for (int j = 0; j < 4; j++) {
        const int rowg = q0 + wave * 32 + tm * 16 + quad * 4 + j;
        float mx = -3.0e38f;
#pragma unroll
        for (int tn = 0; tn < 4; tn++) {
          const int colg = kt + tn * 16 + l16;
          float v = sacc[tm][tn][j];
          v = (colg <= rowg) ? v : -3.0e38f;
          sacc[tm][tn][j] = v;
          mx = fmaxf(mx, v);
        }
        mx = fmaxf(mx, __shfl_xor(mx, 1));
        mx = fmaxf(mx, __shfl_xor(mx, 2));
        mx = fmaxf(mx, __shfl_xor(mx, 4));
        mx = fmaxf(mx, __shfl_xor(mx, 8));
        const float mold = mrow[tm][j];
        const float mnew = fmaxf(mold, mx);
        const float alpha = __expf(mold - mnew);
        mrow[tm][j] = mnew;
        float rs = 0.f;
#pragma unroll
        for (int tn = 0; tn < 4; tn++) {
          float p = __expf(sacc[tm][tn][j] - mnew);
          sacc[tm][tn][j] = p;
          rs += p;
        }
        rs += __shfl_xor(rs, 1);
        rs += __shfl_xor(rs, 2);
        rs += __shfl_xor(rs, 4);
        rs += __shfl_xor(rs, 8);
        lrow[tm][j] = lrow[tm][j] * alpha + rs;
#pragma unroll
        for (int tn2 = 0; tn2 < 8; tn2++) oacc[tm][tn2][j] *= alpha;
      }
    }

    // P: C-layout regs -> LDS -> A-layout frags
#pragma unroll
    for (int tm = 0; tm < 2; tm++)
#pragma unroll
      for (int tn = 0; tn < 4; tn++)
#pragma unroll
        for (int j = 0; j < 4; j++)
          Ps[wave][tm * 16 + quad * 4 + j][tn * 16 + l16] = (bf16)sacc[tm][tn][j];
    __syncthreads();

    // O += P V : 2x8 tiles, K=64 (2 k-steps)
#pragma unroll
    for (int kk2 = 0; kk2 < 2; kk2++) {
      bf16x8 pf[2];
#pragma unroll
      for (int tm = 0; tm < 2; tm++)
        pf[tm] = *reinterpret_cast<const bf16x8*>(&Ps[wave][tm * 16 + l16][kk2 * 32 + quad * 8]);
#pragma unroll
      for (int tn2 = 0; tn2 < 8; tn2++) {
        bf16x8 vf = *reinterpret_cast<const bf16x8*>(&Vts[tn2 * 16 + l16][kk2 * 32 + quad * 8]);
#pragma unroll
        for (int tm = 0; tm < 2; tm++)
          oacc[tm][tn2] = __builtin_amdgcn_mfma_f32_16x16x32_bf16(pf[tm], vf, oacc[tm][tn2], 0, 0, 0);
      }
    }
    __syncthreads();
  }

  // epilogue: O/l -> Y [B][S][D] bf16
  const int b = bh >> 4, h = bh & 15;
#pragma unroll
  for (int tm = 0; tm < 2; tm++) {
    float inv[4];
#pragma unroll
    for (int j = 0; j < 4; j++) inv[j] = 1.0f / lrow[tm][j];
#pragma unroll
    for (int tn2 = 0; tn2 < 8; tn2++) {
#pragma unroll
      for (int j = 0; j < 4; j++) {
        const int srow = q0 + wave * 32 + tm * 16 + quad * 4 + j;
        const int col = h * HD + tn2 * 16 + l16;
        Y[(size_t)(b * SEQ + srow) * DMODEL + col] = (bf16)(oacc[tm][tn2][j] * inv[j]);
      }
    }
  }
}

// ---------------- launch ----------------
extern "C" void kernel_launch(void* const* d_in, const int* in_sizes, int n_in,
                              void* d_out, int out_size, void* d_ws, size_t ws_size,
                              hipStream_t stream) {
  const float* x  = (const float*)d_in[0];
  // d_in[1] = attn_mask (pure causal; implemented analytically)
  const float* Wq = (const float*)d_in[2];
  const float* Wk = (const float*)d_in[3];
  const float* Wv = (const float*)d_in[4];
  const float* Wo = (const float*)d_in[5];
  float* out = (float*)d_out;

  char* ws = (char*)d_ws;
  // workspace layout (bytes); Yb aliases xb (x dead after projections)
  bf16* xb  = (bf16*)(ws + 0);           // 16,777,216 B
  bf16* Wqb = (bf16*)(ws + 16777216);    //  8,388,608 B
  bf16* Wkb = (bf16*)(ws + 25165824);
  bf16* Wvb = (bf16*)(ws + 33554432);
  bf16* Wob = (bf16*)(ws + 41943040);
  bf16* Qb  = (bf16*)(ws + 50331648);    // 16,777,216 B  [B,H,S,d]
  bf16* Kb  = (bf16*)(ws + 67108864);    // [B,H,S,d]
  bf16* Vtb = (bf16*)(ws + 83886080);    // [B,H,d,S]  (ends at 100,663,296)
  bf16* Yb  = xb;                        // [B,S,D]
  if (ws_size < 100663296) return;       // fail visibly rather than corrupt

  const int nx4 = MROWS * DMODEL / 4;    // 2,097,152
  const int nw4 = DMODEL * DMODEL / 4;   // 1,048,576
  cvt_kernel<<<nx4 / 256, 256, 0, stream>>>(x, xb, nx4);
  cvt_kernel<<<nw4 / 256, 256, 0, stream>>>(Wq, Wqb, nw4);
  cvt_kernel<<<nw4 / 256, 256, 0, stream>>>(Wk, Wkb, nw4);
  cvt_kernel<<<nw4 / 256, 256, 0, stream>>>(Wv, Wvb, nw4);
  cvt_kernel<<<nw4 / 256, 256, 0, stream>>>(Wo, Wob, nw4);

  dim3 ggrid(DMODEL / 128, MROWS / 128); // (16, 32)
  gemm_bt<MODE_Q><<<ggrid, 256, 0, stream>>>(xb, Wqb, Qb);
  gemm_bt<MODE_K><<<ggrid, 256, 0, stream>>>(xb, Wkb, Kb);
  gemm_bt<MODE_V><<<ggrid, 256, 0, stream>>>(xb, Wvb, Vtb);

  attn_kernel<<<dim3(SEQ / 128, BATCH * NH), 256, 0, stream>>>(Qb, Kb, Vtb, Yb);

  gemm_bt<MODE_OUT><<<ggrid, 256, 0, stream>>>(Yb, Wob, out);
}

// Round 2
// 504.383 us; speedup vs baseline: 1.0065x; 1.0065x over previous
//
#include <hip/hip_runtime.h>
#include <hip/hip_bf16.h>
#include <cstdint>
#include <cstddef>

typedef __bf16 bf16;
typedef __bf16 bf16x8 __attribute__((ext_vector_type(8)));
typedef __bf16 bf16x4 __attribute__((ext_vector_type(4)));
typedef float f32x4 __attribute__((ext_vector_type(4)));

static constexpr int BATCH = 2;
static constexpr int SEQ = 2048;
static constexpr int DMODEL = 2048;
static constexpr int NH = 16;
static constexpr int HD = 128;
static constexpr int MROWS = BATCH * SEQ; // 4096

#define GLOBAL_AS(p) ((const __attribute__((address_space(1))) void*)(p))
#define LDS_AS(p)    ((__attribute__((address_space(3))) void*)(p))

// ---------------- fp32 -> bf16 convert ----------------
__global__ void cvt_kernel(const float* __restrict__ src, bf16* __restrict__ dst, int n4) {
  int i = blockIdx.x * blockDim.x + threadIdx.x;
  if (i < n4) {
    float4 f = reinterpret_cast<const float4*>(src)[i];
    bf16x4 o;
    o.x = (bf16)f.x; o.y = (bf16)f.y; o.z = (bf16)f.z; o.w = (bf16)f.w;
    reinterpret_cast<bf16x4*>(dst)[i] = o;
  }
}

// ---------------- GEMM: C = A(MxK,row) * W(NxK,row)^T, m97 structure ----------------
// 128x128 tile, 4 waves 2x2 (each 64x64 = 4x4 of 16x16x32 mfma), BK=64,
// global_load_lds dwordx4 staging into UNPADDED LDS (wave-uniform base + lane*16).
enum { MODE_QKV = 0, MODE_OUT = 1 };

template <int MODE>
__global__ __launch_bounds__(256, 2) void gemm_bt(
    const bf16* __restrict__ A, const bf16* __restrict__ W,
    bf16* __restrict__ Oq, bf16* __restrict__ Ok, bf16* __restrict__ Ov,
    float* __restrict__ Oout) {
  constexpr int Kd = DMODEL;
  __shared__ __align__(16) bf16 As[128][64];
  __shared__ __align__(16) bf16 Bs[128][64];
  const int n0 = blockIdx.x * 128;
  const int m0 = blockIdx.y * 128;
  const int tid = threadIdx.x;
  const int wave = tid >> 6;
  const int lane = tid & 63;
  const int quad = lane >> 4;
  const int l16 = lane & 15;
  const int wm = (wave >> 1) * 64;
  const int wn = (wave & 1) * 64;
  const int sr = lane >> 3;        // 0..7 within 8-row chunk
  const int sc = (lane & 7) * 8;   // element col within BK=64

  f32x4 acc[4][4] = {};
  for (int kt = 0; kt < Kd; kt += 64) {
#pragma unroll
    for (int i = 0; i < 4; i++) {
      const int r = wave * 32 + i * 8;
      __builtin_amdgcn_global_load_lds(
          GLOBAL_AS(&A[(size_t)(m0 + r + sr) * Kd + kt + sc]), LDS_AS(&As[r][0]), 16, 0, 0);
      __builtin_amdgcn_global_load_lds(
          GLOBAL_AS(&W[(size_t)(n0 + r + sr) * Kd + kt + sc]), LDS_AS(&Bs[r][0]), 16, 0, 0);
    }
    __syncthreads();
#pragma unroll
    for (int ks = 0; ks < 2; ks++) {
      bf16x8 af[4], bfr[4];
#pragma unroll
      for (int t = 0; t < 4; t++)
        af[t] = *reinterpret_cast<const bf16x8*>(&As[wm + t * 16 + l16][ks * 32 + quad * 8]);
#pragma unroll
      for (int t = 0; t < 4; t++)
        bfr[t] = *reinterpret_cast<const bf16x8*>(&Bs[wn + t * 16 + l16][ks * 32 + quad * 8]);
#pragma unroll
      for (int tm = 0; tm < 4; tm++)
#pragma unroll
        for (int tn = 0; tn < 4; tn++)
          acc[tm][tn] = __builtin_amdgcn_mfma_f32_16x16x32_bf16(af[tm], bfr[tn], acc[tm][tn], 0, 0, 0);
    }
    __syncthreads();
  }
  // epilogue
#pragma unroll
  for (int tm = 0; tm < 4; tm++) {
#pragma unroll
    for (int tn = 0; tn < 4; tn++) {
      const int row0 = m0 + wm + tm * 16 + quad * 4;
      if constexpr (MODE == MODE_OUT) {
        const int col = n0 + wn + tn * 16 + l16;
#pragma unroll
        for (int j = 0; j < 4; j++)
          Oout[(size_t)(row0 + j) * DMODEL + col] = acc[tm][tn][j];
      } else {
        const int mat = n0 >> 11;              // 0=Q 1=K 2=V (wave-uniform per block)
        const int col = (n0 & 2047) + wn + tn * 16 + l16;
        const int h = col >> 7, dd = col & 127;
        if (mat == 2) {
          // V^T layout: Vt[b][h][dd][s], j-regs = 4 consecutive s -> 8B store
          const int b = row0 >> 11, s = row0 & 2047;
          bf16x4 pk;
#pragma unroll
          for (int j = 0; j < 4; j++) pk[j] = (bf16)acc[tm][tn][j];
          *reinterpret_cast<bf16x4*>(&Ov[((size_t)(b * NH + h) * HD + dd) * SEQ + s]) = pk;
        } else {
          bf16* O = mat ? Ok : Oq;
          const float scale = mat ? 1.0f : 0.08838834764831845f;
#pragma unroll
          for (int j = 0; j < 4; j++) {
            const int row = row0 + j;
            const int b = row >> 11, s = row & 2047;
            O[((size_t)(b * NH + h) * SEQ + s) * HD + dd] = (bf16)(acc[tm][tn][j] * scale);
          }
        }
      }
    }
  }
}

// ---------------- flash attention, S^T formulation ----------------
// grid (16 qt, 32 bh), block 256 = 4 waves, wave owns 32 q-rows.
// S^T = K·Q^T so a q-row's scores live in one lane-column: softmax reduction =
// 15 in-lane ops + 2 shuffles (vs 4-deep x 2 chains). O^T = V^T·P^T keeps it.
// Ps aliases Ks (extra barrier) -> LDS 36864 B -> 4 blocks/CU by LDS.
__global__ __launch_bounds__(256, 3) void attn_kernel(
    const bf16* __restrict__ Q, const bf16* __restrict__ K,
    const bf16* __restrict__ Vt, bf16* __restrict__ Y) {
  const int qt = (int)gridDim.x - 1 - (int)blockIdx.x; // long blocks launch first
  const int bh = blockIdx.y;
  const int q0 = qt * 128;
  __shared__ __align__(16) char smem[36864];
  auto Ks  = (bf16(*)[136])smem;           // [64][136]   17408 B (region 0)
  auto Ps  = (bf16(*)[32][72])smem;        // [4][32][72] 18432 B (aliases Ks)
  auto Vts = (bf16(*)[72])(smem + 18432);  // [128][72]   18432 B (region 1)
  const int tid = threadIdx.x;
  const int wave = tid >> 6;
  const int lane = tid & 63;
  const int quad = lane >> 4;
  const int l16 = lane & 15;

  // Q fragments (B-operand: B[k=d][n=q] = Q[q][d]), held in registers
  const bf16* Qw = Q + ((size_t)bh * SEQ + q0 + wave * 32) * HD;
  bf16x8 qf[2][4];
#pragma unroll
  for (int nt = 0; nt < 2; nt++)
#pragma unroll
    for (int kk = 0; kk < 4; kk++)
      qf[nt][kk] = *reinterpret_cast<const bf16x8*>(
          &Qw[(size_t)(nt * 16 + l16) * HD + kk * 32 + quad * 8]);

  f32x4 oacc[8][2] = {};       // O^T[d=mt8*16+quad*4+j][q=nt*16+l16]
  float m_i[2] = {-3.0e38f, -3.0e38f};
  float l_i[2] = {0.f, 0.f};

  const bf16* Kbh = K + (size_t)bh * SEQ * HD;
  const bf16* Vbh = Vt + (size_t)bh * HD * SEQ;
  const int kend = q0 + 128;
  for (int kt = 0; kt < kend; kt += 64) {
    // wave-uniform: this wave's rows are q0+wave*32 .. +31
    const bool active = (kt < q0 + wave * 32 + 32);
    const bool need_mask = (kt + 63 > q0 + wave * 32);

    // ---- stage K (64x128) and Vt (128x64) ----
#pragma unroll
    for (int i = 0; i < 4; i++) {
      int idx = tid + i * 256;
      int r = idx >> 4, c = (idx & 15) * 8;
      *reinterpret_cast<uint4*>(&Ks[r][c]) =
          *reinterpret_cast<const uint4*>(&Kbh[(size_t)(kt + r) * HD + c]);
    }
#pragma unroll
    for (int i = 0; i < 4; i++) {
      int idx = tid + i * 256;
      int r = idx >> 3, c = (idx & 7) * 8;
      *reinterpret_cast<uint4*>(&Vts[r][c]) =
          *reinterpret_cast<const uint4*>(&Vbh[(size_t)r * SEQ + kt + c]);
    }
    __syncthreads();

    f32x4 sacc[4][2] = {};     // S^T[key=mt*16+quad*4+j][q=nt*16+l16]
    if (active) {
      // ---- S^T = K Q^T ----
#pragma unroll
      for (int kk = 0; kk < 4; kk++) {
        bf16x8 ka[4];
#pragma unroll
        for (int mt = 0; mt < 4; mt++)
          ka[mt] = *reinterpret_cast<const bf16x8*>(&Ks[mt * 16 + l16][kk * 32 + quad * 8]);
#pragma unroll
        for (int mt = 0; mt < 4; mt++)
#pragma unroll
          for (int nt = 0; nt < 2; nt++)
            sacc[mt][nt] = __builtin_amdgcn_mfma_f32_16x16x32_bf16(ka[mt], qf[nt][kk], sacc[mt][nt], 0, 0, 0);
      }
      // ---- online softmax (per lane: 2 q-rows, 16 keys each; quads hold rest) ----
#pragma unroll
      for (int nt = 0; nt < 2; nt++) {
        const int qg = q0 + wave * 32 + nt * 16 + l16;
        float mx = -3.0e38f;
        if (need_mask) {
#pragma unroll
          for (int mt = 0; mt < 4; mt++)
#pragma unroll
            for (int j = 0; j < 4; j++) {
              const int kg = kt + mt * 16 + quad * 4 + j;
              float v = (kg <= qg) ? sacc[mt][nt][j] : -3.0e38f;
              sacc[mt][nt][j] = v;
              mx = fmaxf(mx, v);
            }
        } else {
#pragma unroll
          for (int mt = 0; mt < 4; mt++)
#pragma unroll
            for (int j = 0; j < 4; j++) mx = fmaxf(mx, sacc[mt][nt][j]);
        }
        mx = fmaxf(mx, __shfl_xor(mx, 16));
        mx = fmaxf(mx, __shfl_xor(mx, 32));
        const float mold = m_i[nt];
        const float mnew = fmaxf(mold, mx);
        const float alpha = __expf(mold - mnew);
        m_i[nt] = mnew;
        float rs = 0.f;
#pragma unroll
        for (int mt = 0; mt < 4; mt++)
#pragma unroll
          for (int j = 0; j < 4; j++) {
            float p = __expf(sacc[mt][nt][j] - mnew);
            sacc[mt][nt][j] = p;
            rs += p;
          }
        rs += __shfl_xor(rs, 16);
        rs += __shfl_xor(rs, 32);
        l_i[nt] = l_i[nt] * alpha + rs;
#pragma unroll
        for (int mt8 = 0; mt8 < 8; mt8++)
#pragma unroll
          for (int j = 0; j < 4; j++) oacc[mt8][nt][j] *= alpha;
      }
    }
    __syncthreads();   // all waves done reading Ks before Ps overwrite

    if (active) {
      // ---- P^T -> LDS as Ps[q][key] (B-operand layout for PV) ----
#pragma unroll
      for (int nt = 0; nt < 2; nt++)
#pragma unroll
        for (int mt = 0; mt < 4; mt++) {
          bf16x4 pk;
#pragma unroll
          for (int j = 0; j < 4; j++) pk[j] = (bf16)sacc[mt][nt][j];
          *reinterpret_cast<bf16x4*>(&Ps[wave][nt * 16 + l16][mt * 16 + quad * 4]) = pk;
        }
    }
    __syncthreads();

    if (active) {
      // ---- O^T += V^T P^T : A = Vt[d][key], B = Ps[q][key] ----
#pragma unroll
      for (int kk2 = 0; kk2 < 2; kk2++) {
        bf16x8 pb[2];
#pragma unroll
        for (int nt = 0; nt < 2; nt++)
          pb[nt] = *reinterpret_cast<const bf16x8*>(&Ps[wave][nt * 16 + l16][kk2 * 32 + quad * 8]);
#pragma unroll
        for (int mt8 = 0; mt8 < 8; mt8++) {
          bf16x8 av = *reinterpret_cast<const bf16x8*>(&Vts[mt8 * 16 + l16][kk2 * 32 + quad * 8]);
#pragma unroll
          for (int nt = 0; nt < 2; nt++)
            oacc[mt8][nt] = __builtin_amdgcn_mfma_f32_16x16x32_bf16(av, pb[nt], oacc[mt8][nt], 0, 0, 0);
        }
      }
    }
    __syncthreads();   // done reading Ps/Vts before next stage
  }

  // ---- epilogue: O^T/l -> Y[b][s][h*128+d], 8B stores (j-regs = consecutive d) ----
  const int b = bh >> 4, h = bh & 15;
#pragma unroll
  for (int nt = 0; nt < 2; nt++) {
    const float inv = 1.0f / l_i[nt];
    const int qg = q0 + wave * 32 + nt * 16 + l16;
#pragma unroll
    for (int mt8 = 0; mt8 < 8; mt8++) {
      bf16x4 pk;
#pragma unroll
      for (int j = 0; j < 4; j++) pk[j] = (bf16)(oacc[mt8][nt][j] * inv);
      *reinterpret_cast<bf16x4*>(
          &Y[(size_t)(b * SEQ + qg) * DMODEL + h * HD + mt8 * 16 + quad * 4]) = pk;
    }
  }
}

// ---------------- launch ----------------
extern "C" void kernel_launch(void* const* d_in, const int* in_sizes, int n_in,
                              void* d_out, int out_size, void* d_ws, size_t ws_size,
                              hipStream_t stream) {
  const float* x  = (const float*)d_in[0];
  // d_in[1] = attn_mask (pure causal; analytic)
  const float* Wq = (const float*)d_in[2];
  const float* Wk = (const float*)d_in[3];
  const float* Wv = (const float*)d_in[4];
  const float* Wo = (const float*)d_in[5];
  float* out = (float*)d_out;

  char* ws = (char*)d_ws;
  bf16* xb  = (bf16*)(ws + 0);           // 16,777,216 B
  bf16* Wqb = (bf16*)(ws + 16777216);    // Wq,Wk,Wv contiguous -> one [6144][2048]
  bf16* Wkb = (bf16*)(ws + 25165824);
  bf16* Wvb = (bf16*)(ws + 33554432);
  bf16* Wob = (bf16*)(ws + 41943040);
  bf16* Qb  = (bf16*)(ws + 50331648);    // [B,H,S,d]
  bf16* Kb  = (bf16*)(ws + 67108864);    // [B,H,S,d]
  bf16* Vtb = (bf16*)(ws + 83886080);    // [B,H,d,S]
  bf16* Yb  = xb;                        // [B,S,D] (x dead after projections)
  if (ws_size < 100663296) return;

  const int nx4 = MROWS * DMODEL / 4;
  const int nw4 = DMODEL * DMODEL / 4;
  cvt_kernel<<<nx4 / 256, 256, 0, stream>>>(x, xb, nx4);
  cvt_kernel<<<nw4 / 256, 256, 0, stream>>>(Wq, Wqb, nw4);
  cvt_kernel<<<nw4 / 256, 256, 0, stream>>>(Wk, Wkb, nw4);
  cvt_kernel<<<nw4 / 256, 256, 0, stream>>>(Wv, Wvb, nw4);
  cvt_kernel<<<nw4 / 256, 256, 0, stream>>>(Wo, Wob, nw4);

  // fused QKV projection: W3 = [Wq;Wk;Wv] as [6144][2048]
  gemm_bt<MODE_QKV><<<dim3(48, MROWS / 128), 256, 0, stream>>>(
      xb, Wqb, Qb, Kb, Vtb, nullptr);

  attn_kernel<<<dim3(SEQ / 128, BATCH * NH), 256, 0, stream>>>(Qb, Kb, Vtb, Yb);

  gemm_bt<MODE_OUT><<<dim3(16, MROWS / 128), 256, 0, stream>>>(
      Yb, Wob, nullptr, nullptr, nullptr, out);
}